// Round 6
// baseline (405.268 us; speedup 1.0000x reference)
//
#include <hip/hip_runtime.h>
#include <hip/hip_bf16.h>
#include <stdint.h>

typedef __attribute__((ext_vector_type(8))) short short8;   // 8 x bf16 MFMA operand
typedef __attribute__((ext_vector_type(4))) float f32x4;    // MFMA accumulator
typedef unsigned short u16;

#define MFMA(a, b, c) __builtin_amdgcn_mfma_f32_16x16x32_bf16((a), (b), (c), 0, 0, 0)

static __device__ __forceinline__ unsigned pack_bf16(float a, float b) {
  unsigned ua = __float_as_uint(a), ub = __float_as_uint(b);
  ua += 0x7fffu + ((ua >> 16) & 1u);   // RNE
  ub += 0x7fffu + ((ub >> 16) & 1u);
  return (ua >> 16) | (ub & 0xffff0000u);
}
static __device__ __forceinline__ u16 f2bf(float a) {
  unsigned ua = __float_as_uint(a);
  ua += 0x7fffu + ((ua >> 16) & 1u);
  return (u16)(ua >> 16);
}

// ------------------------------------------------------------------
// prep: x fp32 -> bf16
// ------------------------------------------------------------------
__global__ void prep_x_kernel(const float* __restrict__ x, u16* __restrict__ xbf) {
  const size_t N8 = (size_t)65536 * 384 / 8;
  for (size_t i = (size_t)blockIdx.x * 256 + threadIdx.x; i < N8;
       i += (size_t)gridDim.x * 256) {
    const float4* p = (const float4*)(x + i * 8);
    float4 a = p[0], b = p[1];
    uint4 o;
    o.x = pack_bf16(a.x, a.y); o.y = pack_bf16(a.z, a.w);
    o.z = pack_bf16(b.x, b.y); o.w = pack_bf16(b.z, b.w);
    *(uint4*)(xbf + i * 8) = o;
  }
}

// ------------------------------------------------------------------
// prep: tiled transpose w[K][N] -> wT[N][K] bf16 (coalesced both sides)
// ------------------------------------------------------------------
__global__ void prep_wT_kernel(const float* __restrict__ w, u16* __restrict__ wT,
                               int K, int N) {
  __shared__ float t[64][65];
  int nt = N >> 6, bx = blockIdx.x;
  int k0 = (bx / nt) << 6, n0 = (bx - (bx / nt) * nt) << 6;
  int tx = threadIdx.x & 15, ty = threadIdx.x >> 4;
#pragma unroll
  for (int r = 0; r < 4; r++) {
    int k = ty + r * 16;
    float4 v = *(const float4*)&w[(size_t)(k0 + k) * N + n0 + tx * 4];
    t[tx * 4 + 0][k] = v.x; t[tx * 4 + 1][k] = v.y;
    t[tx * 4 + 2][k] = v.z; t[tx * 4 + 3][k] = v.w;
  }
  __syncthreads();
#pragma unroll
  for (int r = 0; r < 4; r++) {
    int n = ty + r * 16;
    const float* row = &t[n][tx * 4];
    ushort4 o;
    o.x = f2bf(row[0]); o.y = f2bf(row[1]); o.z = f2bf(row[2]); o.w = f2bf(row[3]);
    *(ushort4*)&wT[(size_t)(n0 + n) * K + k0 + tx * 4] = o;
  }
}

__global__ void prep_mem_kernel(const float* __restrict__ mem,
                                u16* __restrict__ memK,
                                u16* __restrict__ memvT) {
  int idx = blockIdx.x * 256 + threadIdx.x;
  if (idx < 8 * 64 * 48) {
    int h = idx / (64 * 48);
    int rem = idx - h * (64 * 48);
    int m = rem / 48, d = rem - m * 48;
    u16 v = f2bf(mem[m * 384 + h * 48 + d]);
    memK[(h * 64 + m) * 48 + d] = v;     // [h][m][d]
    memvT[(h * 48 + d) * 64 + m] = v;    // [h][d][m]
  }
}

// ------------------------------------------------------------------
// QKV GEMM v5: NO LDS, NO BARRIERS. Each wave loads MFMA fragments
// directly global->reg (per-lane dwordx4; one lg-quad = one 64B line),
// 1-ahead register double-buffer, 16 MFMA per k-step. B is L2-resident;
// A rows re-read 9x through L2/L3 (450 MB @ 34 TB/s = noise). Waves
// free-run: latency hidden by ILP + 3 waves/SIMD TLP.
// ------------------------------------------------------------------
__global__ __launch_bounds__(256, 3) void qkv_gemm_kernel(
    const u16* __restrict__ xbf, const u16* __restrict__ wT,
    const float* __restrict__ bias,
    u16* __restrict__ qbuf, u16* __restrict__ kbuf, u16* __restrict__ vTb) {
  int tid = threadIdx.x, bx = blockIdx.x;
  int lid = (bx & 7) * 576 + (bx >> 3);   // bijective XCD swizzle (4608 = 8*576)
  int mtile = lid / 9, ntile = lid - mtile * 9;
  int m0 = mtile * 128, n0 = ntile * 128;
  int l = tid & 63, wv = tid >> 6;
  int wr = wv >> 1, wc = wv & 1;
  int lr = l & 15, lg = l >> 4;

  // lane's fragment source rows; frag mi at +mi*16 rows, k-step at +k*32 cols
  const u16* aBase = xbf + (size_t)(m0 + wr * 64 + lr) * 384 + lg * 8;
  const u16* bBase = wT + (size_t)(n0 + wc * 64 + lr) * 384 + lg * 8;

  short8 af[2][4], bfr[2][4];
#define LOADF(s, kk)                                                    \
  do {                                                                  \
    _Pragma("unroll") for (int mi = 0; mi < 4; mi++) {                  \
      af[s][mi] = *(const short8*)(aBase + mi * 6144 + (kk) * 32);      \
      bfr[s][mi] = *(const short8*)(bBase + mi * 6144 + (kk) * 32);     \
    }                                                                   \
  } while (0)

  f32x4 acc[4][4];
#pragma unroll
  for (int i = 0; i < 4; i++)
#pragma unroll
    for (int j = 0; j < 4; j++) acc[i][j] = (f32x4){0.f, 0.f, 0.f, 0.f};

  LOADF(0, 0);
#pragma unroll
  for (int k = 0; k < 12; k++) {
    if (k < 11) LOADF((k + 1) & 1, k + 1);   // static after full unroll
#pragma unroll
    for (int mi = 0; mi < 4; mi++)
#pragma unroll
      for (int ni = 0; ni < 4; ni++)
        acc[mi][ni] = MFMA(af[k & 1][mi], bfr[k & 1][ni], acc[mi][ni]);
  }
#undef LOADF

  const float qscale = 0.14433756729740643f * 1.4426950408889634f;  // scale*log2e
#pragma unroll
  for (int ni = 0; ni < 4; ni++) {
    int n = n0 + wc * 64 + ni * 16 + lr;
    float bn = bias[n];
    int sec = (n >= 768) ? 2 : ((n >= 384) ? 1 : 0);  // block-uniform (128|384)
    int c = n - sec * 384;
    int h = c / 48;
    int d = c - h * 48;
#pragma unroll
    for (int mi = 0; mi < 4; mi++) {
      int mrow = m0 + wr * 64 + mi * 16 + lg * 4;
      int bb = mrow >> 8, t = mrow & 255;
      size_t bh = (size_t)(bb * 8 + h);
      f32x4 a = acc[mi][ni];
      if (sec == 0) {
#pragma unroll
        for (int r = 0; r < 4; r++)
          qbuf[(bh * 256 + (size_t)(t + r)) * 48 + d] = f2bf((a[r] + bn) * qscale);
      } else if (sec == 1) {
#pragma unroll
        for (int r = 0; r < 4; r++)
          kbuf[(bh * 256 + (size_t)(t + r)) * 48 + d] = f2bf(a[r] + bn);
      } else {
        ushort4 o;
        o.x = f2bf(a[0] + bn); o.y = f2bf(a[1] + bn);
        o.z = f2bf(a[2] + bn); o.w = f2bf(a[3] + bn);
        *(ushort4*)(vTb + (bh * 48 + (size_t)d) * 256 + t) = o;  // V transposed
      }
    }
  }
}

// ------------------------------------------------------------------
// Attention (unchanged from passing round-5 version)
// ------------------------------------------------------------------
__global__ __launch_bounds__(256, 2) void attn_kernel(
    const u16* __restrict__ qbuf, const u16* __restrict__ kbuf,
    const u16* __restrict__ vTb, const u16* __restrict__ memK,
    const u16* __restrict__ memvT, u16* __restrict__ ybuf) {
  int bh = blockIdx.x;
  int b = bh >> 3, h = bh & 7;
  int tid = threadIdx.x, l = tid & 63, wv = tid >> 6;
  int lr = l & 15, lg = l >> 4;
  const u16* qb = qbuf + (size_t)bh * 256 * 48;
  const u16* kb = kbuf + (size_t)bh * 256 * 48;
  const u16* vb = vTb + (size_t)bh * 48 * 256;
  const u16* mk = memK + h * 64 * 48;
  const u16* mv = memvT + h * 48 * 64;

  const f32x4 z4 = (f32x4){0.f, 0.f, 0.f, 0.f};

#pragma unroll 1
  for (int qi = 0; qi < 4; qi++) {
    int q0 = wv * 64 + qi * 16;
    int kthi = q0 >> 4;

    const u16* qrow = qb + (q0 + lr) * 48;
    short8 bq0 = *(const short8*)(qrow + lg * 8);
    short8 bq1 = (short8){0, 0, 0, 0, 0, 0, 0, 0};
    if (l < 32) bq1 = *(const short8*)(qrow + 32 + lg * 8);  // feats 32..47

    f32x4 s[9];
#pragma unroll
    for (int mt = 0; mt < 4; mt++) {  // mem tiles: always fully visible
      const u16* krow = mk + (mt * 16 + lr) * 48;
      short8 a0 = *(const short8*)(krow + lg * 8);
      short8 a1 = *(const short8*)(krow + 32 + lg * 8);
      f32x4 sv = MFMA(a0, bq0, z4);
      sv = MFMA(a1, bq1, sv);
      s[mt] = sv;
    }
    int i_q = q0 + lr;
#pragma unroll
    for (int u = 0; u < 5; u++) {  // band tiles kthi-4 .. kthi
      int kt = kthi - 4 + u;
      const u16* krow = kb + (kt * 16 + lr) * 48;  // may be negative: masked
      short8 a0 = *(const short8*)(krow + lg * 8);
      short8 a1 = *(const short8*)(krow + 32 + lg * 8);
      f32x4 sv = MFMA(a0, bq0, z4);
      sv = MFMA(a1, bq1, sv);
#pragma unroll
      for (int r = 0; r < 4; r++) {
        int jk = kt * 16 + lg * 4 + r;
        bool vis = (jk >= 0) && (jk <= i_q) && (i_q - jk <= 64);
        sv[r] = vis ? sv[r] : -1e30f;
      }
      s[4 + u] = sv;
    }

    // softmax over 36 scores/lane + cross-group (same q column) reduce
    float mx = -1e30f;
#pragma unroll
    for (int t = 0; t < 9; t++)
      mx = fmaxf(mx, fmaxf(fmaxf(s[t][0], s[t][1]), fmaxf(s[t][2], s[t][3])));
    mx = fmaxf(mx, __shfl_xor(mx, 16));
    mx = fmaxf(mx, __shfl_xor(mx, 32));
    float sum = 0.f;
#pragma unroll
    for (int t = 0; t < 9; t++) {
#pragma unroll
      for (int r = 0; r < 4; r++) {
        float p = exp2f(s[t][r] - mx);  // scores already in log2 domain
        s[t][r] = p;
        sum += p;
      }
    }
    sum += __shfl_xor(sum, 16);
    sum += __shfl_xor(sum, 32);
    float rinv = 1.f / sum;

    unsigned pk[9][2];
#pragma unroll
    for (int t = 0; t < 9; t++) {
      pk[t][0] = pack_bf16(s[t][0], s[t][1]);
      pk[t][1] = pack_bf16(s[t][2], s[t][3]);
    }

    f32x4 y0 = z4, y1 = z4, y2 = z4;
    auto pv = [&](const u16* vbase, int stride, int lane_ko, unsigned A0,
                  unsigned A1, unsigned B0, unsigned B1, bool hasB) {
      int srcL0 = lr + (lg & 1) * 32;
      int srcL1 = srcL0 + 16;
      bool hi = lg >= 2;
      unsigned a0 = __shfl(A0, srcL0, 64), a1 = __shfl(A1, srcL0, 64);
      unsigned a2 = __shfl(A0, srcL1, 64), a3 = __shfl(A1, srcL1, 64);
      unsigned w0, w1, w2, w3;
      if (hasB) {
        unsigned c0 = __shfl(B0, srcL0, 64), c1 = __shfl(B1, srcL0, 64);
        unsigned c2 = __shfl(B0, srcL1, 64), c3 = __shfl(B1, srcL1, 64);
        w0 = hi ? c0 : a0; w1 = hi ? c1 : a1; w2 = hi ? c2 : a2; w3 = hi ? c3 : a3;
      } else {
        w0 = hi ? 0u : a0; w1 = hi ? 0u : a1; w2 = hi ? 0u : a2; w3 = hi ? 0u : a3;
      }
      union { unsigned u[4]; short8 v; } bu;
      bu.u[0] = w0; bu.u[1] = w1; bu.u[2] = w2; bu.u[3] = w3;
      const u16* va0 = vbase + (0 * 16 + lr) * stride + lane_ko;
      const u16* va1 = vbase + (1 * 16 + lr) * stride + lane_ko;
      const u16* va2 = vbase + (2 * 16 + lr) * stride + lane_ko;
      y0 = MFMA(*(const short8*)va0, bu.v, y0);
      y1 = MFMA(*(const short8*)va1, bu.v, y1);
      y2 = MFMA(*(const short8*)va2, bu.v, y2);
    };
    pv(mv, 64, lg * 8, pk[0][0], pk[0][1], pk[1][0], pk[1][1], true);
    pv(mv + 32, 64, lg * 8, pk[2][0], pk[2][1], pk[3][0], pk[3][1], true);
    const u16* vbb = vb + (kthi - 4) * 16;
    pv(vbb, 256, lg * 8, pk[4][0], pk[4][1], pk[5][0], pk[5][1], true);
    pv(vbb + 32, 256, lg * 8, pk[6][0], pk[6][1], pk[7][0], pk[7][1], true);
    {
      int ko = kthi * 16 + lg * 8;
      if (ko > 248) ko = 0;   // clamp: value multiplies a zero B operand
      pv(vb, 256, ko, pk[8][0], pk[8][1], 0u, 0u, false);
    }

    int t = q0 + lr;
    u16* yout = ybuf + ((size_t)(b * 256 + t)) * 384 + h * 48 + lg * 4;
    ushort4 o;
    o.x = f2bf(y0[0] * rinv); o.y = f2bf(y0[1] * rinv);
    o.z = f2bf(y0[2] * rinv); o.w = f2bf(y0[3] * rinv);
    *(ushort4*)(yout + 0) = o;
    o.x = f2bf(y1[0] * rinv); o.y = f2bf(y1[1] * rinv);
    o.z = f2bf(y1[2] * rinv); o.w = f2bf(y1[3] * rinv);
    *(ushort4*)(yout + 16) = o;
    o.x = f2bf(y2[0] * rinv); o.y = f2bf(y2[1] * rinv);
    o.z = f2bf(y2[2] * rinv); o.w = f2bf(y2[3] * rinv);
    *(ushort4*)(yout + 32) = o;
  }
}

// ------------------------------------------------------------------
// Output projection v5: same no-LDS direct-to-register structure.
// ------------------------------------------------------------------
__global__ __launch_bounds__(256, 3) void proj_gemm_kernel(
    const u16* __restrict__ y, const u16* __restrict__ wT,
    const float* __restrict__ bias, float* __restrict__ out) {
  int tid = threadIdx.x, bx = blockIdx.x;
  int lid = (bx & 7) * 192 + (bx >> 3);  // 1536 = 8 * 192
  int mtile = lid / 3, ntile = lid - mtile * 3;
  int m0 = mtile * 128, n0 = ntile * 128;
  int l = tid & 63, wv = tid >> 6;
  int wr = wv >> 1, wc = wv & 1;
  int lr = l & 15, lg = l >> 4;

  const u16* aBase = y + (size_t)(m0 + wr * 64 + lr) * 384 + lg * 8;
  const u16* bBase = wT + (size_t)(n0 + wc * 64 + lr) * 384 + lg * 8;

  short8 af[2][4], bfr[2][4];
#define LOADF(s, kk)                                                    \
  do {                                                                  \
    _Pragma("unroll") for (int mi = 0; mi < 4; mi++) {                  \
      af[s][mi] = *(const short8*)(aBase + mi * 6144 + (kk) * 32);      \
      bfr[s][mi] = *(const short8*)(bBase + mi * 6144 + (kk) * 32);     \
    }                                                                   \
  } while (0)

  f32x4 acc[4][4];
#pragma unroll
  for (int i = 0; i < 4; i++)
#pragma unroll
    for (int j = 0; j < 4; j++) acc[i][j] = (f32x4){0.f, 0.f, 0.f, 0.f};

  LOADF(0, 0);
#pragma unroll
  for (int k = 0; k < 12; k++) {
    if (k < 11) LOADF((k + 1) & 1, k + 1);
#pragma unroll
    for (int mi = 0; mi < 4; mi++)
#pragma unroll
      for (int ni = 0; ni < 4; ni++)
        acc[mi][ni] = MFMA(af[k & 1][mi], bfr[k & 1][ni], acc[mi][ni]);
  }
#undef LOADF

#pragma unroll
  for (int ni = 0; ni < 4; ni++) {
    int n = n0 + wc * 64 + ni * 16 + lr;
    float bn = bias[n];
#pragma unroll
    for (int mi = 0; mi < 4; mi++) {
      int mrow = m0 + wr * 64 + mi * 16 + lg * 4;
      f32x4 a = acc[mi][ni];
#pragma unroll
      for (int r = 0; r < 4; r++)
        out[(size_t)(mrow + r) * 384 + n] = a[r] + bn;
    }
  }
}

// ------------------------------------------------------------------
extern "C" void kernel_launch(void* const* d_in, const int* in_sizes, int n_in,
                              void* d_out, int out_size, void* d_ws, size_t ws_size,
                              hipStream_t stream) {
  (void)in_sizes; (void)n_in; (void)out_size; (void)ws_size;
  const float* x = (const float*)d_in[0];
  const float* mem = (const float*)d_in[1];
  const float* qkv_w = (const float*)d_in[2];
  const float* qkv_b = (const float*)d_in[3];
  const float* proj_w = (const float*)d_in[4];
  const float* proj_b = (const float*)d_in[5];
  float* out = (float*)d_out;

  char* ws = (char*)d_ws;
  size_t off = 0;
  auto alloc = [&](size_t bytes) -> void* {
    void* p = (void*)(ws + off);
    off += (bytes + 255) & ~(size_t)255;
    return p;
  };
  // order matters: small negative/positive overreads in attn land in the
  // adjacent buffers (finite bf16 data, multiplied by zero) -- keep this order.
  u16* qkv_wT = (u16*)alloc((size_t)1152 * 384 * 2);
  u16* proj_wT = (u16*)alloc((size_t)384 * 384 * 2);
  u16* memK = (u16*)alloc((size_t)8 * 64 * 48 * 2);
  u16* memvT = (u16*)alloc((size_t)8 * 48 * 64 * 2);
  u16* qbuf = (u16*)alloc((size_t)2048 * 256 * 48 * 2);
  u16* kbuf = (u16*)alloc((size_t)2048 * 256 * 48 * 2);
  u16* vTb = (u16*)alloc((size_t)2048 * 48 * 256 * 2);
  u16* ybuf = (u16*)alloc((size_t)65536 * 384 * 2);
  u16* xbf = ybuf;  // alias: xbf dead after qkv_gemm; attn then writes ybuf

  hipLaunchKernelGGL(prep_wT_kernel, dim3(108), dim3(256), 0, stream,
                     qkv_w, qkv_wT, 384, 1152);
  hipLaunchKernelGGL(prep_wT_kernel, dim3(36), dim3(256), 0, stream,
                     proj_w, proj_wT, 384, 384);
  hipLaunchKernelGGL(prep_mem_kernel, dim3(96), dim3(256), 0, stream,
                     mem, memK, memvT);
  hipLaunchKernelGGL(prep_x_kernel, dim3(4096), dim3(256), 0, stream, x, xbf);
  hipLaunchKernelGGL(qkv_gemm_kernel, dim3(4608), dim3(256), 0, stream,
                     xbf, qkv_wT, qkv_b, qbuf, kbuf, vTb);
  hipLaunchKernelGGL(attn_kernel, dim3(2048), dim3(256), 0, stream,
                     qbuf, kbuf, vTb, memK, memvT, ybuf);
  hipLaunchKernelGGL(proj_gemm_kernel, dim3(1536), dim3(256), 0, stream,
                     ybuf, proj_wT, proj_b, out);
}

// Round 7
// 263.142 us; speedup vs baseline: 1.5401x; 1.5401x over previous
//
#include <hip/hip_runtime.h>
#include <hip/hip_bf16.h>
#include <stdint.h>

typedef __attribute__((ext_vector_type(8))) short short8;   // 8 x bf16 MFMA operand
typedef __attribute__((ext_vector_type(4))) float f32x4;    // MFMA accumulator
typedef unsigned short u16;

#define MFMA(a, b, c) __builtin_amdgcn_mfma_f32_16x16x32_bf16((a), (b), (c), 0, 0, 0)

static __device__ __forceinline__ unsigned pack_bf16(float a, float b) {
  unsigned ua = __float_as_uint(a), ub = __float_as_uint(b);
  ua += 0x7fffu + ((ua >> 16) & 1u);   // RNE
  ub += 0x7fffu + ((ub >> 16) & 1u);
  return (ua >> 16) | (ub & 0xffff0000u);
}
static __device__ __forceinline__ u16 f2bf(float a) {
  unsigned ua = __float_as_uint(a);
  ua += 0x7fffu + ((ua >> 16) & 1u);
  return (u16)(ua >> 16);
}

// 16B-wide async global->LDS DMA. LDS dest: wave-uniform base + lane*16.
#define GLD16(gsrc, ldst)                                                     \
  __builtin_amdgcn_global_load_lds(                                           \
      (const __attribute__((address_space(1))) unsigned int*)(gsrc),          \
      (__attribute__((address_space(3))) unsigned int*)(ldst), 16, 0, 0)

#define VMCNT0() asm volatile("s_waitcnt vmcnt(0)" ::: "memory")
#define VMCNT4() asm volatile("s_waitcnt vmcnt(4)" ::: "memory")
#define BARRIER()                         \
  do {                                    \
    __builtin_amdgcn_s_barrier();         \
    __builtin_amdgcn_sched_barrier(0);    \
  } while (0)

// ------------------------------------------------------------------
// prep: x fp32 -> bf16
// ------------------------------------------------------------------
__global__ void prep_x_kernel(const float* __restrict__ x, u16* __restrict__ xbf) {
  const size_t N8 = (size_t)65536 * 384 / 8;
  for (size_t i = (size_t)blockIdx.x * 256 + threadIdx.x; i < N8;
       i += (size_t)gridDim.x * 256) {
    const float4* p = (const float4*)(x + i * 8);
    float4 a = p[0], b = p[1];
    uint4 o;
    o.x = pack_bf16(a.x, a.y); o.y = pack_bf16(a.z, a.w);
    o.z = pack_bf16(b.x, b.y); o.w = pack_bf16(b.z, b.w);
    *(uint4*)(xbf + i * 8) = o;
  }
}

// ------------------------------------------------------------------
// prep: tiled transpose w[K][N] -> wT[N][K] bf16 (coalesced both sides)
// ------------------------------------------------------------------
__global__ void prep_wT_kernel(const float* __restrict__ w, u16* __restrict__ wT,
                               int K, int N) {
  __shared__ float t[64][65];
  int nt = N >> 6, bx = blockIdx.x;
  int k0 = (bx / nt) << 6, n0 = (bx - (bx / nt) * nt) << 6;
  int tx = threadIdx.x & 15, ty = threadIdx.x >> 4;
#pragma unroll
  for (int r = 0; r < 4; r++) {
    int k = ty + r * 16;
    float4 v = *(const float4*)&w[(size_t)(k0 + k) * N + n0 + tx * 4];
    t[tx * 4 + 0][k] = v.x; t[tx * 4 + 1][k] = v.y;
    t[tx * 4 + 2][k] = v.z; t[tx * 4 + 3][k] = v.w;
  }
  __syncthreads();
#pragma unroll
  for (int r = 0; r < 4; r++) {
    int n = ty + r * 16;
    const float* row = &t[n][tx * 4];
    ushort4 o;
    o.x = f2bf(row[0]); o.y = f2bf(row[1]); o.z = f2bf(row[2]); o.w = f2bf(row[3]);
    *(ushort4*)&wT[(size_t)(n0 + n) * K + k0 + tx * 4] = o;
  }
}

__global__ void prep_mem_kernel(const float* __restrict__ mem,
                                u16* __restrict__ memK,
                                u16* __restrict__ memvT) {
  int idx = blockIdx.x * 256 + threadIdx.x;
  if (idx < 8 * 64 * 48) {
    int h = idx / (64 * 48);
    int rem = idx - h * (64 * 48);
    int m = rem / 48, d = rem - m * 48;
    u16 v = f2bf(mem[m * 384 + h * 48 + d]);
    memK[(h * 64 + m) * 48 + d] = v;     // [h][m][d]
    memvT[(h * 48 + d) * 64 + m] = v;    // [h][d][m]
  }
}

// ------------------------------------------------------------------
// QKV GEMM v6: loop identical to round-5 (GLD16 staging, 3-buffer,
// counted vmcnt(4)). NEW: epilogue bounces the 128x128 output tile
// through LDS so ALL global stores are coalesced 16B pieces covering
// contiguous 256B row chunks (16 lanes/row -> full 64B lines).
// q,k now stored FLAT [65536][384]; V^T unchanged [bh][48][256] but
// written via a col-major LDS bounce.
// ------------------------------------------------------------------
__global__ __launch_bounds__(256, 3) void qkv_gemm_kernel(
    const u16* __restrict__ xbf, const u16* __restrict__ wT,
    const float* __restrict__ bias,
    u16* __restrict__ qf, u16* __restrict__ kf, u16* __restrict__ vTb) {
  __shared__ u16 LDSU[24576];   // staging: A = [0,12288), B = [12288,24576)
                                // bounce tile: [0,17408) reused after loop
  u16* Abase = LDSU;
  u16* Bbase = LDSU + 12288;
  int tid = threadIdx.x, bx = blockIdx.x;
  int lid = (bx & 7) * 576 + (bx >> 3);   // bijective XCD swizzle (4608 = 8*576)
  int mtile = lid / 9, ntile = lid - mtile * 9;
  int m0 = mtile * 128, n0 = ntile * 128;
  int l = tid & 63, wv = tid >> 6;
  int wr = wv >> 1, wc = wv & 1;
  int lr = l & 15, lg = l >> 4;

  int q = l >> 2, g = l & 3;
  int rA0 = wv * 32 + q, rA1 = rA0 + 16;
  const u16* sA0 = xbf + (size_t)(m0 + rA0) * 384 + (g ^ ((rA0 >> 1) & 3)) * 8;
  const u16* sA1 = xbf + (size_t)(m0 + rA1) * 384 + (g ^ ((rA1 >> 1) & 3)) * 8;
  const u16* sB0 = wT + (size_t)(n0 + rA0) * 384 + (g ^ ((rA0 >> 1) & 3)) * 8;
  const u16* sB1 = wT + (size_t)(n0 + rA1) * 384 + (g ^ ((rA1 >> 1) & 3)) * 8;

#define STAGE(j)                                            \
  do {                                                      \
    int b_ = (j) % 3;                                       \
    GLD16(sA0 + (j) * 32, Abase + b_ * 4096 + wv * 1024);   \
    GLD16(sA1 + (j) * 32, Abase + b_ * 4096 + wv * 1024 + 512); \
    GLD16(sB0 + (j) * 32, Bbase + b_ * 4096 + wv * 1024);   \
    GLD16(sB1 + (j) * 32, Bbase + b_ * 4096 + wv * 1024 + 512); \
  } while (0)

  int ra[4], rb[4];
#pragma unroll
  for (int i = 0; i < 4; i++) {
    int rA = wr * 64 + i * 16 + lr;
    ra[i] = rA * 32 + (lg ^ ((rA >> 1) & 3)) * 8;
    int rB = wc * 64 + i * 16 + lr;
    rb[i] = rB * 32 + (lg ^ ((rB >> 1) & 3)) * 8;
  }

  f32x4 acc[4][4];
#pragma unroll
  for (int i = 0; i < 4; i++)
#pragma unroll
    for (int j = 0; j < 4; j++) acc[i][j] = (f32x4){0.f, 0.f, 0.f, 0.f};

  STAGE(0);
  STAGE(1);
  VMCNT4();   // stage 0 landed; stage 1 (4 loads) still in flight
  BARRIER();

#pragma unroll
  for (int k = 0; k < 12; k++) {
    if (k < 10) STAGE(k + 2);
    short8 af[4], bfr[4];
#pragma unroll
    for (int mi = 0; mi < 4; mi++)
      af[mi] = *(const short8*)(Abase + (k % 3) * 4096 + ra[mi]);
#pragma unroll
    for (int ni = 0; ni < 4; ni++)
      bfr[ni] = *(const short8*)(Bbase + (k % 3) * 4096 + rb[ni]);
#pragma unroll
    for (int mi = 0; mi < 4; mi++)
#pragma unroll
      for (int ni = 0; ni < 4; ni++)
        acc[mi][ni] = MFMA(af[mi], bfr[ni], acc[mi][ni]);
    if (k < 11) {
      if (k < 10) VMCNT4(); else VMCNT0();
      BARRIER();
    }
  }
#undef STAGE

  // ---------------- bounce epilogue ----------------
  __syncthreads();   // all waves done reading staging LDS
  const float qscale = 0.14433756729740643f * 1.4426950408889634f;  // scale*log2e
  int sec = ntile / 3;   // 0=q 1=k 2=v (block-uniform; 384 = 3*128)
  int jp = (l & 15) * 8;

  if (sec < 2) {
    float scl = (sec == 0) ? qscale : 1.0f;
#pragma unroll
    for (int ni = 0; ni < 4; ni++) {
      int col = wc * 64 + ni * 16 + lr;
      float bn = bias[n0 + col];
#pragma unroll
      for (int mi = 0; mi < 4; mi++) {
        int row0 = wr * 64 + mi * 16 + lg * 4;
        f32x4 a = acc[mi][ni];
#pragma unroll
        for (int r = 0; r < 4; r++)
          LDSU[(row0 + r) * 136 + col] = f2bf((a[r] + bn) * scl);
      }
    }
    __syncthreads();
    u16* dst = (sec == 0) ? qf : kf;
    int cq = n0 - sec * 384;   // 0..255 col base within [BT][384]
#pragma unroll
    for (int i = 0; i < 8; i++) {
      int row = wv * 32 + i * 4 + (l >> 4);
      uint4 v = *(const uint4*)&LDSU[row * 136 + jp];
      *(uint4*)&dst[(size_t)(m0 + row) * 384 + cq + jp] = v;
    }
  } else {
    // V: col-major bounce [c:128][t:136] so frag rows pack into b64 writes
#pragma unroll
    for (int ni = 0; ni < 4; ni++) {
      int c = wc * 64 + ni * 16 + lr;
      float bn = bias[n0 + c];
#pragma unroll
      for (int mi = 0; mi < 4; mi++) {
        int t0 = wr * 64 + mi * 16 + lg * 4;
        f32x4 a = acc[mi][ni];
        ushort4 o;
        o.x = f2bf(a[0] + bn); o.y = f2bf(a[1] + bn);
        o.z = f2bf(a[2] + bn); o.w = f2bf(a[3] + bn);
        *(ushort4*)&LDSU[c * 136 + t0] = o;
      }
    }
    __syncthreads();
    size_t vrow0 = (size_t)((m0 >> 8) * 384 + (n0 - 768));  // bh*48+d linear
    int tb = m0 & 255;
#pragma unroll
    for (int i = 0; i < 8; i++) {
      int c = wv * 32 + i * 4 + (l >> 4);
      uint4 v = *(const uint4*)&LDSU[c * 136 + jp];
      *(uint4*)&vTb[(vrow0 + c) * 256 + tb + jp] = v;
    }
  }
}

// ------------------------------------------------------------------
// Attention: q,k now read from FLAT [65536][384] layout (row stride 384,
// head offset h*48). Everything else unchanged from passing round-5.
// ------------------------------------------------------------------
__global__ __launch_bounds__(256, 2) void attn_kernel(
    const u16* __restrict__ qf, const u16* __restrict__ kf,
    const u16* __restrict__ vTb, const u16* __restrict__ memK,
    const u16* __restrict__ memvT, u16* __restrict__ ybuf) {
  int bh = blockIdx.x;
  int b = bh >> 3, h = bh & 7;
  int tid = threadIdx.x, l = tid & 63, wv = tid >> 6;
  int lr = l & 15, lg = l >> 4;
  const u16* qb = qf + (size_t)b * 256 * 384 + h * 48;
  const u16* kb = kf + (size_t)b * 256 * 384 + h * 48;
  const u16* vb = vTb + (size_t)bh * 48 * 256;
  const u16* mk = memK + h * 64 * 48;
  const u16* mv = memvT + h * 48 * 64;

  const f32x4 z4 = (f32x4){0.f, 0.f, 0.f, 0.f};

#pragma unroll 1
  for (int qi = 0; qi < 4; qi++) {
    int q0 = wv * 64 + qi * 16;
    int kthi = q0 >> 4;

    const u16* qrow = qb + (size_t)(q0 + lr) * 384;
    short8 bq0 = *(const short8*)(qrow + lg * 8);
    short8 bq1 = (short8){0, 0, 0, 0, 0, 0, 0, 0};
    if (l < 32) bq1 = *(const short8*)(qrow + 32 + lg * 8);  // feats 32..47

    f32x4 s[9];
#pragma unroll
    for (int mt = 0; mt < 4; mt++) {  // mem tiles: always fully visible
      const u16* krow = mk + (mt * 16 + lr) * 48;
      short8 a0 = *(const short8*)(krow + lg * 8);
      short8 a1 = *(const short8*)(krow + 32 + lg * 8);
      f32x4 sv = MFMA(a0, bq0, z4);
      sv = MFMA(a1, bq1, sv);
      s[mt] = sv;
    }
    int i_q = q0 + lr;
#pragma unroll
    for (int u = 0; u < 5; u++) {  // band tiles kthi-4 .. kthi
      int kt = kthi - 4 + u;
      const u16* krow = kb + (ptrdiff_t)(kt * 16 + lr) * 384;  // may be neg: masked
      short8 a0 = *(const short8*)(krow + lg * 8);
      short8 a1 = *(const short8*)(krow + 32 + lg * 8);
      f32x4 sv = MFMA(a0, bq0, z4);
      sv = MFMA(a1, bq1, sv);
#pragma unroll
      for (int r = 0; r < 4; r++) {
        int jk = kt * 16 + lg * 4 + r;
        bool vis = (jk >= 0) && (jk <= i_q) && (i_q - jk <= 64);
        sv[r] = vis ? sv[r] : -1e30f;
      }
      s[4 + u] = sv;
    }

    // softmax over 36 scores/lane + cross-group (same q column) reduce
    float mx = -1e30f;
#pragma unroll
    for (int t = 0; t < 9; t++)
      mx = fmaxf(mx, fmaxf(fmaxf(s[t][0], s[t][1]), fmaxf(s[t][2], s[t][3])));
    mx = fmaxf(mx, __shfl_xor(mx, 16));
    mx = fmaxf(mx, __shfl_xor(mx, 32));
    float sum = 0.f;
#pragma unroll
    for (int t = 0; t < 9; t++) {
#pragma unroll
      for (int r = 0; r < 4; r++) {
        float p = exp2f(s[t][r] - mx);  // scores already in log2 domain
        s[t][r] = p;
        sum += p;
      }
    }
    sum += __shfl_xor(sum, 16);
    sum += __shfl_xor(sum, 32);
    float rinv = 1.f / sum;

    unsigned pk[9][2];
#pragma unroll
    for (int t = 0; t < 9; t++) {
      pk[t][0] = pack_bf16(s[t][0], s[t][1]);
      pk[t][1] = pack_bf16(s[t][2], s[t][3]);
    }

    f32x4 y0 = z4, y1 = z4, y2 = z4;
    auto pv = [&](const u16* vbase, int stride, int lane_ko, unsigned A0,
                  unsigned A1, unsigned B0, unsigned B1, bool hasB) {
      int srcL0 = lr + (lg & 1) * 32;
      int srcL1 = srcL0 + 16;
      bool hi = lg >= 2;
      unsigned a0 = __shfl(A0, srcL0, 64), a1 = __shfl(A1, srcL0, 64);
      unsigned a2 = __shfl(A0, srcL1, 64), a3 = __shfl(A1, srcL1, 64);
      unsigned w0, w1, w2, w3;
      if (hasB) {
        unsigned c0 = __shfl(B0, srcL0, 64), c1 = __shfl(B1, srcL0, 64);
        unsigned c2 = __shfl(B0, srcL1, 64), c3 = __shfl(B1, srcL1, 64);
        w0 = hi ? c0 : a0; w1 = hi ? c1 : a1; w2 = hi ? c2 : a2; w3 = hi ? c3 : a3;
      } else {
        w0 = hi ? 0u : a0; w1 = hi ? 0u : a1; w2 = hi ? 0u : a2; w3 = hi ? 0u : a3;
      }
      union { unsigned u[4]; short8 v; } bu;
      bu.u[0] = w0; bu.u[1] = w1; bu.u[2] = w2; bu.u[3] = w3;
      const u16* va0 = vbase + (0 * 16 + lr) * stride + lane_ko;
      const u16* va1 = vbase + (1 * 16 + lr) * stride + lane_ko;
      const u16* va2 = vbase + (2 * 16 + lr) * stride + lane_ko;
      y0 = MFMA(*(const short8*)va0, bu.v, y0);
      y1 = MFMA(*(const short8*)va1, bu.v, y1);
      y2 = MFMA(*(const short8*)va2, bu.v, y2);
    };
    pv(mv, 64, lg * 8, pk[0][0], pk[0][1], pk[1][0], pk[1][1], true);
    pv(mv + 32, 64, lg * 8, pk[2][0], pk[2][1], pk[3][0], pk[3][1], true);
    const u16* vbb = vb + (kthi - 4) * 16;
    pv(vbb, 256, lg * 8, pk[4][0], pk[4][1], pk[5][0], pk[5][1], true);
    pv(vbb + 32, 256, lg * 8, pk[6][0], pk[6][1], pk[7][0], pk[7][1], true);
    {
      int ko = kthi * 16 + lg * 8;
      if (ko > 248) ko = 0;   // clamp: value multiplies a zero B operand
      pv(vb, 256, ko, pk[8][0], pk[8][1], 0u, 0u, false);
    }

    int t = q0 + lr;
    u16* yout = ybuf + ((size_t)(b * 256 + t)) * 384 + h * 48 + lg * 4;
    ushort4 o;
    o.x = f2bf(y0[0] * rinv); o.y = f2bf(y0[1] * rinv);
    o.z = f2bf(y0[2] * rinv); o.w = f2bf(y0[3] * rinv);
    *(ushort4*)(yout + 0) = o;
    o.x = f2bf(y1[0] * rinv); o.y = f2bf(y1[1] * rinv);
    o.z = f2bf(y1[2] * rinv); o.w = f2bf(y1[3] * rinv);
    *(ushort4*)(yout + 16) = o;
    o.x = f2bf(y2[0] * rinv); o.y = f2bf(y2[1] * rinv);
    o.z = f2bf(y2[2] * rinv); o.w = f2bf(y2[3] * rinv);
    *(ushort4*)(yout + 32) = o;
  }
}

// ------------------------------------------------------------------
// Output projection: round-5 pipeline (fp32 out is already coalesced:
// lanes store consecutive n -> 64B chunks).
// ------------------------------------------------------------------
__global__ __launch_bounds__(256, 3) void proj_gemm_kernel(
    const u16* __restrict__ y, const u16* __restrict__ wT,
    const float* __restrict__ bias, float* __restrict__ out) {
  __shared__ u16 Al[3][4096];
  __shared__ u16 Bl[3][4096];
  int tid = threadIdx.x, bx = blockIdx.x;
  int lid = (bx & 7) * 192 + (bx >> 3);  // 1536 = 8 * 192
  int mtile = lid / 3, ntile = lid - mtile * 3;
  int m0 = mtile * 128, n0 = ntile * 128;
  int l = tid & 63, wv = tid >> 6;
  int wr = wv >> 1, wc = wv & 1;
  int lr = l & 15, lg = l >> 4;

  int q = l >> 2, g = l & 3;
  int rA0 = wv * 32 + q, rA1 = rA0 + 16;
  const u16* sA0 = y + (size_t)(m0 + rA0) * 384 + (g ^ ((rA0 >> 1) & 3)) * 8;
  const u16* sA1 = y + (size_t)(m0 + rA1) * 384 + (g ^ ((rA1 >> 1) & 3)) * 8;
  const u16* sB0 = wT + (size_t)(n0 + rA0) * 384 + (g ^ ((rA0 >> 1) & 3)) * 8;
  const u16* sB1 = wT + (size_t)(n0 + rA1) * 384 + (g ^ ((rA1 >> 1) & 3)) * 8;

#define STAGE(j)                                          \
  do {                                                    \
    int b_ = (j) % 3;                                     \
    GLD16(sA0 + (j) * 32, &Al[b_][wv * 1024]);            \
    GLD16(sA1 + (j) * 32, &Al[b_][wv * 1024 + 512]);      \
    GLD16(sB0 + (j) * 32, &Bl[b_][wv * 1024]);            \
    GLD16(sB1 + (j) * 32, &Bl[b_][wv * 1024 + 512]);      \
  } while (0)

  int ra[4], rb[4];
#pragma unroll
  for (int i = 0; i < 4; i++) {
    int rA = wr * 64 + i * 16 + lr;
    ra[i] = rA * 32 + (lg ^ ((rA >> 1) & 3)) * 8;
    int rB = wc * 64 + i * 16 + lr;
    rb[i] = rB * 32 + (lg ^ ((rB >> 1) & 3)) * 8;
  }

  f32x4 acc[4][4];
#pragma unroll
  for (int i = 0; i < 4; i++)
#pragma unroll
    for (int j = 0; j < 4; j++) acc[i][j] = (f32x4){0.f, 0.f, 0.f, 0.f};

  STAGE(0);
  STAGE(1);
  VMCNT4();
  BARRIER();

#pragma unroll
  for (int k = 0; k < 12; k++) {
    if (k < 10) STAGE(k + 2);
    short8 af[4], bfr[4];
#pragma unroll
    for (int mi = 0; mi < 4; mi++) af[mi] = *(const short8*)&Al[k % 3][ra[mi]];
#pragma unroll
    for (int ni = 0; ni < 4; ni++) bfr[ni] = *(const short8*)&Bl[k % 3][rb[ni]];
#pragma unroll
    for (int mi = 0; mi < 4; mi++)
#pragma unroll
      for (int ni = 0; ni < 4; ni++)
        acc[mi][ni] = MFMA(af[mi], bfr[ni], acc[mi][ni]);
    if (k < 11) {
      if (k < 10) VMCNT4(); else VMCNT0();
      BARRIER();
    }
  }
#undef STAGE

#pragma unroll
  for (int ni = 0; ni < 4; ni++) {
    int n = n0 + wc * 64 + ni * 16 + lr;
    float bn = bias[n];
#pragma unroll
    for (int mi = 0; mi < 4; mi++) {
      int mrow = m0 + wr * 64 + mi * 16 + lg * 4;
      f32x4 a = acc[mi][ni];
#pragma unroll
      for (int r = 0; r < 4; r++)
        out[(size_t)(mrow + r) * 384 + n] = a[r] + bn;
    }
  }
}

// ------------------------------------------------------------------
extern "C" void kernel_launch(void* const* d_in, const int* in_sizes, int n_in,
                              void* d_out, int out_size, void* d_ws, size_t ws_size,
                              hipStream_t stream) {
  (void)in_sizes; (void)n_in; (void)out_size; (void)ws_size;
  const float* x = (const float*)d_in[0];
  const float* mem = (const float*)d_in[1];
  const float* qkv_w = (const float*)d_in[2];
  const float* qkv_b = (const float*)d_in[3];
  const float* proj_w = (const float*)d_in[4];
  const float* proj_b = (const float*)d_in[5];
  float* out = (float*)d_out;

  char* ws = (char*)d_ws;
  size_t off = 0;
  auto alloc = [&](size_t bytes) -> void* {
    void* p = (void*)(ws + off);
    off += (bytes + 255) & ~(size_t)255;
    return p;
  };
  // order matters: attn band tiles with negative key rows read below kf
  // (must land in qf: finite bf16, multiplied by zero) -- keep qf before kf.
  u16* qkv_wT = (u16*)alloc((size_t)1152 * 384 * 2);
  u16* proj_wT = (u16*)alloc((size_t)384 * 384 * 2);
  u16* memK = (u16*)alloc((size_t)8 * 64 * 48 * 2);
  u16* memvT = (u16*)alloc((size_t)8 * 48 * 64 * 2);
  u16* qf = (u16*)alloc((size_t)65536 * 384 * 2);
  u16* kf = (u16*)alloc((size_t)65536 * 384 * 2);
  u16* vTb = (u16*)alloc((size_t)2048 * 48 * 256 * 2);
  u16* ybuf = (u16*)alloc((size_t)65536 * 384 * 2);
  u16* xbf = ybuf;  // alias: xbf dead after qkv_gemm; attn then writes ybuf

  hipLaunchKernelGGL(prep_wT_kernel, dim3(108), dim3(256), 0, stream,
                     qkv_w, qkv_wT, 384, 1152);
  hipLaunchKernelGGL(prep_wT_kernel, dim3(36), dim3(256), 0, stream,
                     proj_w, proj_wT, 384, 384);
  hipLaunchKernelGGL(prep_mem_kernel, dim3(96), dim3(256), 0, stream,
                     mem, memK, memvT);
  hipLaunchKernelGGL(prep_x_kernel, dim3(4096), dim3(256), 0, stream, x, xbf);
  hipLaunchKernelGGL(qkv_gemm_kernel, dim3(4608), dim3(256), 0, stream,
                     xbf, qkv_wT, qkv_b, qf, kf, vTb);
  hipLaunchKernelGGL(attn_kernel, dim3(2048), dim3(256), 0, stream,
                     qf, kf, vTb, memK, memvT, ybuf);
  hipLaunchKernelGGL(proj_gemm_kernel, dim3(1536), dim3(256), 0, stream,
                     ybuf, proj_wT, proj_b, out);
}

// Round 10
// 224.365 us; speedup vs baseline: 1.8063x; 1.1728x over previous
//
#include <hip/hip_runtime.h>
#include <hip/hip_bf16.h>
#include <stdint.h>

typedef __attribute__((ext_vector_type(8))) short short8;   // 8 x bf16 MFMA operand
typedef __attribute__((ext_vector_type(4))) float f32x4;    // MFMA accumulator
typedef unsigned short u16;

#define MFMA(a, b, c) __builtin_amdgcn_mfma_f32_16x16x32_bf16((a), (b), (c), 0, 0, 0)

static __device__ __forceinline__ unsigned pack_bf16(float a, float b) {
  unsigned ua = __float_as_uint(a), ub = __float_as_uint(b);
  ua += 0x7fffu + ((ua >> 16) & 1u);   // RNE
  ub += 0x7fffu + ((ub >> 16) & 1u);
  return (ua >> 16) | (ub & 0xffff0000u);
}
static __device__ __forceinline__ u16 f2bf(float a) {
  unsigned ua = __float_as_uint(a);
  ua += 0x7fffu + ((ua >> 16) & 1u);
  return (u16)(ua >> 16);
}

// 16B-wide async global->LDS DMA. LDS dest: wave-uniform base + lane*16.
#define GLD16(gsrc, ldst)                                                     \
  __builtin_amdgcn_global_load_lds(                                           \
      (const __attribute__((address_space(1))) unsigned int*)(gsrc),          \
      (__attribute__((address_space(3))) unsigned int*)(ldst), 16, 0, 0)

#define VMCNT0() asm volatile("s_waitcnt vmcnt(0)" ::: "memory")
#define VMCNT4() asm volatile("s_waitcnt vmcnt(4)" ::: "memory")
#define BARRIER()                         \
  do {                                    \
    __builtin_amdgcn_s_barrier();         \
    __builtin_amdgcn_sched_barrier(0);    \
  } while (0)

// ------------------------------------------------------------------
// prep: x fp32 -> bf16
// ------------------------------------------------------------------
__global__ void prep_x_kernel(const float* __restrict__ x, u16* __restrict__ xbf) {
  const size_t N8 = (size_t)65536 * 384 / 8;
  for (size_t i = (size_t)blockIdx.x * 256 + threadIdx.x; i < N8;
       i += (size_t)gridDim.x * 256) {
    const float4* p = (const float4*)(x + i * 8);
    float4 a = p[0], b = p[1];
    uint4 o;
    o.x = pack_bf16(a.x, a.y); o.y = pack_bf16(a.z, a.w);
    o.z = pack_bf16(b.x, b.y); o.w = pack_bf16(b.z, b.w);
    *(uint4*)(xbf + i * 8) = o;
  }
}

// ------------------------------------------------------------------
// prep: tiled transpose w[K][N] -> wT[N][K] bf16 (coalesced both sides)
// ------------------------------------------------------------------
__global__ void prep_wT_kernel(const float* __restrict__ w, u16* __restrict__ wT,
                               int K, int N) {
  __shared__ float t[64][65];
  int nt = N >> 6, bx = blockIdx.x;
  int k0 = (bx / nt) << 6, n0 = (bx - (bx / nt) * nt) << 6;
  int tx = threadIdx.x & 15, ty = threadIdx.x >> 4;
#pragma unroll
  for (int r = 0; r < 4; r++) {
    int k = ty + r * 16;
    float4 v = *(const float4*)&w[(size_t)(k0 + k) * N + n0 + tx * 4];
    t[tx * 4 + 0][k] = v.x; t[tx * 4 + 1][k] = v.y;
    t[tx * 4 + 2][k] = v.z; t[tx * 4 + 3][k] = v.w;
  }
  __syncthreads();
#pragma unroll
  for (int r = 0; r < 4; r++) {
    int n = ty + r * 16;
    const float* row = &t[n][tx * 4];
    ushort4 o;
    o.x = f2bf(row[0]); o.y = f2bf(row[1]); o.z = f2bf(row[2]); o.w = f2bf(row[3]);
    *(ushort4*)&wT[(size_t)(n0 + n) * K + k0 + tx * 4] = o;
  }
}

__global__ void prep_mem_kernel(const float* __restrict__ mem,
                                u16* __restrict__ memK,
                                u16* __restrict__ memvT) {
  int idx = blockIdx.x * 256 + threadIdx.x;
  if (idx < 8 * 64 * 48) {
    int h = idx / (64 * 48);
    int rem = idx - h * (64 * 48);
    int m = rem / 48, d = rem - m * 48;
    u16 v = f2bf(mem[m * 384 + h * 48 + d]);
    memK[(h * 64 + m) * 48 + d] = v;     // [h][m][d]
    memvT[(h * 48 + d) * 64 + m] = v;    // [h][d][m]
  }
}

// ------------------------------------------------------------------
// QKV GEMM (EXACT round-7 kernel, replay-proven): GLD16 staging,
// 3-buffer counted-vmcnt pipeline, LDS-bounce epilogue, FLAT q/k out.
// ------------------------------------------------------------------
__global__ __launch_bounds__(256, 3) void qkv_gemm_kernel(
    const u16* __restrict__ xbf, const u16* __restrict__ wT,
    const float* __restrict__ bias,
    u16* __restrict__ qf, u16* __restrict__ kf, u16* __restrict__ vTb) {
  __shared__ u16 LDSU[24576];   // staging: A = [0,12288), B = [12288,24576)
                                // bounce tile: [0,17408) reused after loop
  u16* Abase = LDSU;
  u16* Bbase = LDSU + 12288;
  int tid = threadIdx.x, bx = blockIdx.x;
  int lid = (bx & 7) * 576 + (bx >> 3);   // bijective XCD swizzle (4608 = 8*576)
  int mtile = lid / 9, ntile = lid - mtile * 9;
  int m0 = mtile * 128, n0 = ntile * 128;
  int l = tid & 63, wv = tid >> 6;
  int wr = wv >> 1, wc = wv & 1;
  int lr = l & 15, lg = l >> 4;

  int q = l >> 2, g = l & 3;
  int rA0 = wv * 32 + q, rA1 = rA0 + 16;
  const u16* sA0 = xbf + (size_t)(m0 + rA0) * 384 + (g ^ ((rA0 >> 1) & 3)) * 8;
  const u16* sA1 = xbf + (size_t)(m0 + rA1) * 384 + (g ^ ((rA1 >> 1) & 3)) * 8;
  const u16* sB0 = wT + (size_t)(n0 + rA0) * 384 + (g ^ ((rA0 >> 1) & 3)) * 8;
  const u16* sB1 = wT + (size_t)(n0 + rA1) * 384 + (g ^ ((rA1 >> 1) & 3)) * 8;

#define STAGE(j)                                            \
  do {                                                      \
    int b_ = (j) % 3;                                       \
    GLD16(sA0 + (j) * 32, Abase + b_ * 4096 + wv * 1024);   \
    GLD16(sA1 + (j) * 32, Abase + b_ * 4096 + wv * 1024 + 512); \
    GLD16(sB0 + (j) * 32, Bbase + b_ * 4096 + wv * 1024);   \
    GLD16(sB1 + (j) * 32, Bbase + b_ * 4096 + wv * 1024 + 512); \
  } while (0)

  int ra[4], rb[4];
#pragma unroll
  for (int i = 0; i < 4; i++) {
    int rA = wr * 64 + i * 16 + lr;
    ra[i] = rA * 32 + (lg ^ ((rA >> 1) & 3)) * 8;
    int rB = wc * 64 + i * 16 + lr;
    rb[i] = rB * 32 + (lg ^ ((rB >> 1) & 3)) * 8;
  }

  f32x4 acc[4][4];
#pragma unroll
  for (int i = 0; i < 4; i++)
#pragma unroll
    for (int j = 0; j < 4; j++) acc[i][j] = (f32x4){0.f, 0.f, 0.f, 0.f};

  STAGE(0);
  STAGE(1);
  VMCNT4();   // stage 0 landed; stage 1 (4 loads) still in flight
  BARRIER();

#pragma unroll
  for (int k = 0; k < 12; k++) {
    if (k < 10) STAGE(k + 2);
    short8 af[4], bfr[4];
#pragma unroll
    for (int mi = 0; mi < 4; mi++)
      af[mi] = *(const short8*)(Abase + (k % 3) * 4096 + ra[mi]);
#pragma unroll
    for (int ni = 0; ni < 4; ni++)
      bfr[ni] = *(const short8*)(Bbase + (k % 3) * 4096 + rb[ni]);
#pragma unroll
    for (int mi = 0; mi < 4; mi++)
#pragma unroll
      for (int ni = 0; ni < 4; ni++)
        acc[mi][ni] = MFMA(af[mi], bfr[ni], acc[mi][ni]);
    if (k < 11) {
      if (k < 10) VMCNT4(); else VMCNT0();
      BARRIER();
    }
  }
#undef STAGE

  // ---------------- bounce epilogue ----------------
  __syncthreads();   // all waves done reading staging LDS
  const float qscale = 0.14433756729740643f * 1.4426950408889634f;  // scale*log2e
  int sec = ntile / 3;   // 0=q 1=k 2=v (block-uniform; 384 = 3*128)
  int jp = (l & 15) * 8;

  if (sec < 2) {
    float scl = (sec == 0) ? qscale : 1.0f;
#pragma unroll
    for (int ni = 0; ni < 4; ni++) {
      int col = wc * 64 + ni * 16 + lr;
      float bn = bias[n0 + col];
#pragma unroll
      for (int mi = 0; mi < 4; mi++) {
        int row0 = wr * 64 + mi * 16 + lg * 4;
        f32x4 a = acc[mi][ni];
#pragma unroll
        for (int r = 0; r < 4; r++)
          LDSU[(row0 + r) * 136 + col] = f2bf((a[r] + bn) * scl);
      }
    }
    __syncthreads();
    u16* dst = (sec == 0) ? qf : kf;
    int cq = n0 - sec * 384;   // 0..255 col base within [BT][384]
#pragma unroll
    for (int i = 0; i < 8; i++) {
      int row = wv * 32 + i * 4 + (l >> 4);
      uint4 v = *(const uint4*)&LDSU[row * 136 + jp];
      *(uint4*)&dst[(size_t)(m0 + row) * 384 + cq + jp] = v;
    }
  } else {
    // V: col-major bounce [c:128][t:136] so frag rows pack into b64 writes
#pragma unroll
    for (int ni = 0; ni < 4; ni++) {
      int c = wc * 64 + ni * 16 + lr;
      float bn = bias[n0 + c];
#pragma unroll
      for (int mi = 0; mi < 4; mi++) {
        int t0 = wr * 64 + mi * 16 + lg * 4;
        f32x4 a = acc[mi][ni];
        ushort4 o;
        o.x = f2bf(a[0] + bn); o.y = f2bf(a[1] + bn);
        o.z = f2bf(a[2] + bn); o.w = f2bf(a[3] + bn);
        *(ushort4*)&LDSU[c * 136 + t0] = o;
      }
    }
    __syncthreads();
    size_t vrow0 = (size_t)((m0 >> 8) * 384 + (n0 - 768));  // bh*48+d linear
    int tb = m0 & 255;
#pragma unroll
    for (int i = 0; i < 8; i++) {
      int c = wv * 32 + i * 4 + (l >> 4);
      uint4 v = *(const uint4*)&LDSU[c * 136 + jp];
      *(uint4*)&vTb[(vrow0 + c) * 256 + tb + jp] = v;
    }
  }
}

// ------------------------------------------------------------------
// Attention v3: K head-slice staged into LDS once per block.
// FIX vs round 9: Klds padded +16 u16 and pad zero-initialized -- the
// band-tile a1 read (krow+32+lg*8, kr=255, lg>=2) reaches 12304 u16;
// unpadded this was an LDS OOB read of undefined residue (possible
// bf16-NaN pattern; NaN*0=NaN in MFMA) => replay-dependent corruption.
// Staging barrier is a full __syncthreads (orders pad ds_writes too).
// ------------------------------------------------------------------
__global__ __launch_bounds__(256, 2) void attn_kernel(
    const u16* __restrict__ qf, const u16* __restrict__ kf,
    const u16* __restrict__ vTb, const u16* __restrict__ memK,
    const u16* __restrict__ memvT, u16* __restrict__ ybuf) {
  __shared__ u16 Klds[256 * 48 + 16];   // dense [t:256][d:48] + overread pad
  int bh = blockIdx.x;
  int b = bh >> 3, h = bh & 7;
  int tid = threadIdx.x, l = tid & 63, wv = tid >> 6;
  int lr = l & 15, lg = l >> 4;
  const u16* qb = qf + (size_t)b * 256 * 384 + h * 48;
  const u16* kfb = kf + (size_t)b * 256 * 384 + h * 48;
  const u16* vb = vTb + (size_t)bh * 48 * 256;
  const u16* mk = memK + h * 64 * 48;
  const u16* mv = memvT + h * 48 * 64;

  // stage K: 1536 x 16B granules; granule idx -> (t = idx/6, gi = idx%6)
#pragma unroll
  for (int j = 0; j < 6; j++) {
    int wb = j * 256 + wv * 64;        // wave-uniform granule base
    int idx = wb + l;
    int t = idx / 6, gi = idx - t * 6;
    GLD16(kfb + (size_t)t * 384 + gi * 8, Klds + wb * 8);
  }
  if (tid < 16) Klds[256 * 48 + tid] = 0;   // deterministic pad (read x B=0)
  VMCNT0();
  __syncthreads();   // drains lgkmcnt (pad writes) + joins DMA visibility

  const f32x4 z4 = (f32x4){0.f, 0.f, 0.f, 0.f};

#pragma unroll 1
  for (int qi = 0; qi < 4; qi++) {
    int q0 = wv * 64 + qi * 16;
    int kthi = q0 >> 4;

    const u16* qrow = qb + (size_t)(q0 + lr) * 384;
    short8 bq0 = *(const short8*)(qrow + lg * 8);
    short8 bq1 = (short8){0, 0, 0, 0, 0, 0, 0, 0};
    if (l < 32) bq1 = *(const short8*)(qrow + 32 + lg * 8);  // feats 32..47

    f32x4 s[9];
#pragma unroll
    for (int mt = 0; mt < 4; mt++) {  // mem tiles: always fully visible
      const u16* krow = mk + (mt * 16 + lr) * 48;
      short8 a0 = *(const short8*)(krow + lg * 8);
      short8 a1 = *(const short8*)(krow + 32 + lg * 8);
      f32x4 sv = MFMA(a0, bq0, z4);
      sv = MFMA(a1, bq1, sv);
      s[mt] = sv;
    }
    int i_q = q0 + lr;
#pragma unroll
    for (int u = 0; u < 5; u++) {  // band tiles kthi-4 .. kthi
      int kt = kthi - 4 + u;
      int kr = kt * 16 + lr;
      if (kr < 0) kr = 0;   // fully-masked tile: value irrelevant, keep in-bounds
      const u16* krow = (const u16*)Klds + kr * 48;
      short8 a0 = *(const short8*)(krow + lg * 8);
      short8 a1 = *(const short8*)(krow + 32 + lg * 8);  // pad-covered overread
      f32x4 sv = MFMA(a0, bq0, z4);
      sv = MFMA(a1, bq1, sv);
#pragma unroll
      for (int r = 0; r < 4; r++) {
        int jk = kt * 16 + lg * 4 + r;
        bool vis = (jk >= 0) && (jk <= i_q) && (i_q - jk <= 64);
        sv[r] = vis ? sv[r] : -1e30f;
      }
      s[4 + u] = sv;
    }

    // softmax over 36 scores/lane + cross-group (same q column) reduce
    float mx = -1e30f;
#pragma unroll
    for (int t = 0; t < 9; t++)
      mx = fmaxf(mx, fmaxf(fmaxf(s[t][0], s[t][1]), fmaxf(s[t][2], s[t][3])));
    mx = fmaxf(mx, __shfl_xor(mx, 16));
    mx = fmaxf(mx, __shfl_xor(mx, 32));
    float sum = 0.f;
#pragma unroll
    for (int t = 0; t < 9; t++) {
#pragma unroll
      for (int r = 0; r < 4; r++) {
        float p = exp2f(s[t][r] - mx);  // scores already in log2 domain
        s[t][r] = p;
        sum += p;
      }
    }
    sum += __shfl_xor(sum, 16);
    sum += __shfl_xor(sum, 32);
    float rinv = 1.f / sum;

    unsigned pk[9][2];
#pragma unroll
    for (int t = 0; t < 9; t++) {
      pk[t][0] = pack_bf16(s[t][0], s[t][1]);
      pk[t][1] = pack_bf16(s[t][2], s[t][3]);
    }

    f32x4 y0 = z4, y1 = z4, y2 = z4;
    auto pv = [&](const u16* vbase, int stride, int lane_ko, unsigned A0,
                  unsigned A1, unsigned B0, unsigned B1, bool hasB) {
      int srcL0 = lr + (lg & 1) * 32;
      int srcL1 = srcL0 + 16;
      bool hi = lg >= 2;
      unsigned a0 = __shfl(A0, srcL0, 64), a1 = __shfl(A1, srcL0, 64);
      unsigned a2 = __shfl(A0, srcL1, 64), a3 = __shfl(A1, srcL1, 64);
      unsigned w0, w1, w2, w3;
      if (hasB) {
        unsigned c0 = __shfl(B0, srcL0, 64), c1 = __shfl(B1, srcL0, 64);
        unsigned c2 = __shfl(B0, srcL1, 64), c3 = __shfl(B1, srcL1, 64);
        w0 = hi ? c0 : a0; w1 = hi ? c1 : a1; w2 = hi ? c2 : a2; w3 = hi ? c3 : a3;
      } else {
        w0 = hi ? 0u : a0; w1 = hi ? 0u : a1; w2 = hi ? 0u : a2; w3 = hi ? 0u : a3;
      }
      union { unsigned u[4]; short8 v; } bu;
      bu.u[0] = w0; bu.u[1] = w1; bu.u[2] = w2; bu.u[3] = w3;
      const u16* va0 = vbase + (0 * 16 + lr) * stride + lane_ko;
      const u16* va1 = vbase + (1 * 16 + lr) * stride + lane_ko;
      const u16* va2 = vbase + (2 * 16 + lr) * stride + lane_ko;
      y0 = MFMA(*(const short8*)va0, bu.v, y0);
      y1 = MFMA(*(const short8*)va1, bu.v, y1);
      y2 = MFMA(*(const short8*)va2, bu.v, y2);
    };
    pv(mv, 64, lg * 8, pk[0][0], pk[0][1], pk[1][0], pk[1][1], true);
    pv(mv + 32, 64, lg * 8, pk[2][0], pk[2][1], pk[3][0], pk[3][1], true);
    const u16* vbb = vb + (kthi - 4) * 16;
    pv(vbb, 256, lg * 8, pk[4][0], pk[4][1], pk[5][0], pk[5][1], true);
    pv(vbb + 32, 256, lg * 8, pk[6][0], pk[6][1], pk[7][0], pk[7][1], true);
    {
      int ko = kthi * 16 + lg * 8;
      if (ko > 248) ko = 0;   // clamp: value multiplies a zero B operand
      pv(vb, 256, ko, pk[8][0], pk[8][1], 0u, 0u, false);
    }

    int t = q0 + lr;
    u16* yout = ybuf + ((size_t)(b * 256 + t)) * 384 + h * 48 + lg * 4;
    ushort4 o;
    o.x = f2bf(y0[0] * rinv); o.y = f2bf(y0[1] * rinv);
    o.z = f2bf(y0[2] * rinv); o.w = f2bf(y0[3] * rinv);
    *(ushort4*)(yout + 0) = o;
    o.x = f2bf(y1[0] * rinv); o.y = f2bf(y1[1] * rinv);
    o.z = f2bf(y1[2] * rinv); o.w = f2bf(y1[3] * rinv);
    *(ushort4*)(yout + 16) = o;
    o.x = f2bf(y2[0] * rinv); o.y = f2bf(y2[1] * rinv);
    o.z = f2bf(y2[2] * rinv); o.w = f2bf(y2[3] * rinv);
    *(ushort4*)(yout + 32) = o;
  }
}

// ------------------------------------------------------------------
// Output projection (EXACT round-7 kernel, replay-proven).
// ------------------------------------------------------------------
__global__ __launch_bounds__(256, 3) void proj_gemm_kernel(
    const u16* __restrict__ y, const u16* __restrict__ wT,
    const float* __restrict__ bias, float* __restrict__ out) {
  __shared__ u16 Al[3][4096];
  __shared__ u16 Bl[3][4096];
  int tid = threadIdx.x, bx = blockIdx.x;
  int lid = (bx & 7) * 192 + (bx >> 3);  // 1536 = 8 * 192
  int mtile = lid / 3, ntile = lid - mtile * 3;
  int m0 = mtile * 128, n0 = ntile * 128;
  int l = tid & 63, wv = tid >> 6;
  int wr = wv >> 1, wc = wv & 1;
  int lr = l & 15, lg = l >> 4;

  int q = l >> 2, g = l & 3;
  int rA0 = wv * 32 + q, rA1 = rA0 + 16;
  const u16* sA0 = y + (size_t)(m0 + rA0) * 384 + (g ^ ((rA0 >> 1) & 3)) * 8;
  const u16* sA1 = y + (size_t)(m0 + rA1) * 384 + (g ^ ((rA1 >> 1) & 3)) * 8;
  const u16* sB0 = wT + (size_t)(n0 + rA0) * 384 + (g ^ ((rA0 >> 1) & 3)) * 8;
  const u16* sB1 = wT + (size_t)(n0 + rA1) * 384 + (g ^ ((rA1 >> 1) & 3)) * 8;

#define STAGE(j)                                          \
  do {                                                    \
    int b_ = (j) % 3;                                     \
    GLD16(sA0 + (j) * 32, &Al[b_][wv * 1024]);            \
    GLD16(sA1 + (j) * 32, &Al[b_][wv * 1024 + 512]);      \
    GLD16(sB0 + (j) * 32, &Bl[b_][wv * 1024]);            \
    GLD16(sB1 + (j) * 32, &Bl[b_][wv * 1024 + 512]);      \
  } while (0)

  int ra[4], rb[4];
#pragma unroll
  for (int i = 0; i < 4; i++) {
    int rA = wr * 64 + i * 16 + lr;
    ra[i] = rA * 32 + (lg ^ ((rA >> 1) & 3)) * 8;
    int rB = wc * 64 + i * 16 + lr;
    rb[i] = rB * 32 + (lg ^ ((rB >> 1) & 3)) * 8;
  }

  f32x4 acc[4][4];
#pragma unroll
  for (int i = 0; i < 4; i++)
#pragma unroll
    for (int j = 0; j < 4; j++) acc[i][j] = (f32x4){0.f, 0.f, 0.f, 0.f};

  STAGE(0);
  STAGE(1);
  VMCNT4();
  BARRIER();

#pragma unroll
  for (int k = 0; k < 12; k++) {
    if (k < 10) STAGE(k + 2);
    short8 af[4], bfr[4];
#pragma unroll
    for (int mi = 0; mi < 4; mi++) af[mi] = *(const short8*)&Al[k % 3][ra[mi]];
#pragma unroll
    for (int ni = 0; ni < 4; ni++) bfr[ni] = *(const short8*)&Bl[k % 3][rb[ni]];
#pragma unroll
    for (int mi = 0; mi < 4; mi++)
#pragma unroll
      for (int ni = 0; ni < 4; ni++)
        acc[mi][ni] = MFMA(af[mi], bfr[ni], acc[mi][ni]);
    if (k < 11) {
      if (k < 10) VMCNT4(); else VMCNT0();
      BARRIER();
    }
  }
#undef STAGE

#pragma unroll
  for (int ni = 0; ni < 4; ni++) {
    int n = n0 + wc * 64 + ni * 16 + lr;
    float bn = bias[n];
#pragma unroll
    for (int mi = 0; mi < 4; mi++) {
      int mrow = m0 + wr * 64 + mi * 16 + lg * 4;
      f32x4 a = acc[mi][ni];
#pragma unroll
      for (int r = 0; r < 4; r++)
        out[(size_t)(mrow + r) * 384 + n] = a[r] + bn;
    }
  }
}

// ------------------------------------------------------------------
extern "C" void kernel_launch(void* const* d_in, const int* in_sizes, int n_in,
                              void* d_out, int out_size, void* d_ws, size_t ws_size,
                              hipStream_t stream) {
  (void)in_sizes; (void)n_in; (void)out_size; (void)ws_size;
  const float* x = (const float*)d_in[0];
  const float* mem = (const float*)d_in[1];
  const float* qkv_w = (const float*)d_in[2];
  const float* qkv_b = (const float*)d_in[3];
  const float* proj_w = (const float*)d_in[4];
  const float* proj_b = (const float*)d_in[5];
  float* out = (float*)d_out;

  char* ws = (char*)d_ws;
  size_t off = 0;
  auto alloc = [&](size_t bytes) -> void* {
    void* p = (void*)(ws + off);
    off += (bytes + 255) & ~(size_t)255;
    return p;
  };
  u16* qkv_wT = (u16*)alloc((size_t)1152 * 384 * 2);
  u16* proj_wT = (u16*)alloc((size_t)384 * 384 * 2);
  u16* memK = (u16*)alloc((size_t)8 * 64 * 48 * 2);
  u16* memvT = (u16*)alloc((size_t)8 * 48 * 64 * 2);
  u16* qf = (u16*)alloc((size_t)65536 * 384 * 2);
  u16* kf = (u16*)alloc((size_t)65536 * 384 * 2);
  u16* vTb = (u16*)alloc((size_t)2048 * 48 * 256 * 2);
  u16* ybuf = (u16*)alloc((size_t)65536 * 384 * 2);
  u16* xbf = ybuf;  // alias: xbf dead after qkv_gemm; attn then writes ybuf

  hipLaunchKernelGGL(prep_wT_kernel, dim3(108), dim3(256), 0, stream,
                     qkv_w, qkv_wT, 384, 1152);
  hipLaunchKernelGGL(prep_wT_kernel, dim3(36), dim3(256), 0, stream,
                     proj_w, proj_wT, 384, 384);
  hipLaunchKernelGGL(prep_mem_kernel, dim3(96), dim3(256), 0, stream,
                     mem, memK, memvT);
  hipLaunchKernelGGL(prep_x_kernel, dim3(4096), dim3(256), 0, stream, x, xbf);
  hipLaunchKernelGGL(qkv_gemm_kernel, dim3(4608), dim3(256), 0, stream,
                     xbf, qkv_wT, qkv_b, qf, kf, vTb);
  hipLaunchKernelGGL(attn_kernel, dim3(2048), dim3(256), 0, stream,
                     qf, kf, vTb, memK, memvT, ybuf);
  hipLaunchKernelGGL(proj_gemm_kernel, dim3(1536), dim3(256), 0, stream,
                     ybuf, proj_wT, proj_b, out);
}

// Round 12
// 189.810 us; speedup vs baseline: 2.1351x; 1.1820x over previous
//
#include <hip/hip_runtime.h>
#include <hip/hip_bf16.h>
#include <stdint.h>

typedef __attribute__((ext_vector_type(8))) short short8;   // 8 x bf16 MFMA operand
typedef __attribute__((ext_vector_type(4))) float f32x4;    // MFMA accumulator
typedef unsigned short u16;

#define MFMA(a, b, c) __builtin_amdgcn_mfma_f32_16x16x32_bf16((a), (b), (c), 0, 0, 0)

static __device__ __forceinline__ unsigned pack_bf16(float a, float b) {
  unsigned ua = __float_as_uint(a), ub = __float_as_uint(b);
  ua += 0x7fffu + ((ua >> 16) & 1u);   // RNE
  ub += 0x7fffu + ((ub >> 16) & 1u);
  return (ua >> 16) | (ub & 0xffff0000u);
}
static __device__ __forceinline__ u16 f2bf(float a) {
  unsigned ua = __float_as_uint(a);
  ua += 0x7fffu + ((ua >> 16) & 1u);
  return (u16)(ua >> 16);
}

// 16B-wide async global->LDS DMA. LDS dest: wave-uniform base + lane*16.
#define GLD16(gsrc, ldst)                                                     \
  __builtin_amdgcn_global_load_lds(                                           \
      (const __attribute__((address_space(1))) unsigned int*)(gsrc),          \
      (__attribute__((address_space(3))) unsigned int*)(ldst), 16, 0, 0)

#define VMCNT0() asm volatile("s_waitcnt vmcnt(0)" ::: "memory")
#define VMCNT4() asm volatile("s_waitcnt vmcnt(4)" ::: "memory")
#define BARRIER()                         \
  do {                                    \
    __builtin_amdgcn_s_barrier();         \
    __builtin_amdgcn_sched_barrier(0);    \
  } while (0)

#define QSCALE (0.14433756729740643f * 1.4426950408889634f)  // hd^-0.5 * log2e

// ------------------------------------------------------------------
// prep: x fp32 -> bf16 (round-10 exact)
// ------------------------------------------------------------------
__global__ void prep_x_kernel(const float* __restrict__ x, u16* __restrict__ xbf) {
  const size_t N8 = (size_t)65536 * 384 / 8;
  for (size_t i = (size_t)blockIdx.x * 256 + threadIdx.x; i < N8;
       i += (size_t)gridDim.x * 256) {
    const float4* p = (const float4*)(x + i * 8);
    float4 a = p[0], b = p[1];
    uint4 o;
    o.x = pack_bf16(a.x, a.y); o.y = pack_bf16(a.z, a.w);
    o.z = pack_bf16(b.x, b.y); o.w = pack_bf16(b.z, b.w);
    *(uint4*)(xbf + i * 8) = o;
  }
}

// ------------------------------------------------------------------
// prep: tiled transpose w[K][N] -> wT[N][K] bf16 (round-10 exact; proj only)
// ------------------------------------------------------------------
__global__ void prep_wT_kernel(const float* __restrict__ w, u16* __restrict__ wT,
                               int K, int N) {
  __shared__ float t[64][65];
  int nt = N >> 6, bx = blockIdx.x;
  int k0 = (bx / nt) << 6, n0 = (bx - (bx / nt) * nt) << 6;
  int tx = threadIdx.x & 15, ty = threadIdx.x >> 4;
#pragma unroll
  for (int r = 0; r < 4; r++) {
    int k = ty + r * 16;
    float4 v = *(const float4*)&w[(size_t)(k0 + k) * N + n0 + tx * 4];
    t[tx * 4 + 0][k] = v.x; t[tx * 4 + 1][k] = v.y;
    t[tx * 4 + 2][k] = v.z; t[tx * 4 + 3][k] = v.w;
  }
  __syncthreads();
#pragma unroll
  for (int r = 0; r < 4; r++) {
    int n = ty + r * 16;
    const float* row = &t[n][tx * 4];
    ushort4 o;
    o.x = f2bf(row[0]); o.y = f2bf(row[1]); o.z = f2bf(row[2]); o.w = f2bf(row[3]);
    *(ushort4*)&wT[(size_t)(n0 + n) * K + k0 + tx * 4] = o;
  }
}

__global__ void prep_mem_kernel(const float* __restrict__ mem,
                                u16* __restrict__ memK,
                                u16* __restrict__ memvT) {
  int idx = blockIdx.x * 256 + threadIdx.x;
  if (idx < 8 * 64 * 48) {
    int h = idx / (64 * 48);
    int rem = idx - h * (64 * 48);
    int m = rem / 48, d = rem - m * 48;
    u16 v = f2bf(mem[m * 384 + h * 48 + d]);
    memK[(h * 64 + m) * 48 + d] = v;     // [h][m][d]
    memvT[(h * 48 + d) * 64 + m] = v;    // [h][d][m]
  }
}

// ------------------------------------------------------------------
// prep: per-head qkv weight slab wH[h][192][384] bf16 (rows 0-47 = Wq^T
// pre-scaled by QSCALE, 48-95 = Wk^T, 96-143 = Wv^T, 144-191 = zero pad
// for DMA alignment) + matching bias bH[h][192] f32 (q rows pre-scaled).
// qkv_w is 1.7 MB -> L2-resident; scattered reads are cheap.
// ------------------------------------------------------------------
__global__ void prep_wh_kernel(const float* __restrict__ qkv_w,
                               const float* __restrict__ qkv_b,
                               u16* __restrict__ wH, float* __restrict__ bH) {
  int idx = blockIdx.x * 256 + threadIdx.x;
  if (idx < 8 * 192 * 384) {
    int h = idx / (192 * 384);
    int rem = idx - h * (192 * 384);
    int r = rem / 384, kk = rem - r * 384;
    float v = 0.f;
    if (r < 144) {
      int n = (r < 48) ? (h * 48 + r)
            : (r < 96) ? (384 + h * 48 + (r - 48))
                       : (768 + h * 48 + (r - 96));
      float s = (r < 48) ? QSCALE : 1.f;
      v = qkv_w[(size_t)kk * 1152 + n] * s;
    }
    wH[idx] = f2bf(v);
  }
  if (idx < 8 * 192) {
    int h = idx / 192, r = idx - h * 192;
    float v = 0.f;
    if (r < 144) {
      int n = (r < 48) ? (h * 48 + r)
            : (r < 96) ? (384 + h * 48 + (r - 48))
                       : (768 + h * 48 + (r - 96));
      v = qkv_b[n] * ((r < 48) ? QSCALE : 1.f);
    }
    bH[idx] = v;
  }
}

// ------------------------------------------------------------------
// FUSED qkv-projection + attention. One block per (b,h), 256 thr, 4 waves.
// Phase 1: GEMM q|k|v = x[b] @ wH[h] (M=256, N=144(+48 pad), K=384),
//   GLD16 staging, 2-buffer dbuf, XOR-swizzled LDS (proven scheme).
// Phase 2: acc -> LDS q[256][48], k[256][56]+pad16(zeroed), vT[48][264].
// Phase 3: round-10 attention verbatim, q/k/v from LDS.
// LDS union 78.6 KB -> 2 blocks/CU. q/k/v NEVER touch global memory.
// ------------------------------------------------------------------
#define QOFF 0        // q  [256][48]      12288 u16
#define KOFF 12288    // k  [256][56]+16   14352 u16
#define VOFF 26640    // vT [48][264]      12672 u16
                      // total 39312 u16 = 78624 B
                      // staging overlay: Ab0@0(8192) Ab1@8192 Bb0@16384(6144) Bb1@22528

__global__ __launch_bounds__(256, 2) void fused_qkv_attn_kernel(
    const u16* __restrict__ xbf, const u16* __restrict__ wH,
    const float* __restrict__ bH, const u16* __restrict__ memK,
    const u16* __restrict__ memvT, u16* __restrict__ ybuf) {
  __shared__ u16 L[39312];
  int tid = threadIdx.x, bx = blockIdx.x;
  int bh = (bx & 7) * 256 + (bx >> 3);   // same-b heads grouped per XCD
  int b = bh >> 3, h = bh & 7;
  int l = tid & 63, wv = tid >> 6;
  int lr = l & 15, lg = l >> 4;

  const u16* xb = xbf + (size_t)b * 256 * 384;
  const u16* wh = wH + (size_t)h * 192 * 384;

  // staging sources: granule idx = it*256+tid -> (row=idx>>2, g=idx&3),
  // global granule pre-swizzled g ^ ((row>>1)&3); LDS dest linear idx*16B.
  const u16* srcA[4];
  const u16* srcB[3];
#pragma unroll
  for (int it = 0; it < 4; it++) {
    int idx = it * 256 + tid, row = idx >> 2, g = idx & 3;
    srcA[it] = xb + (size_t)row * 384 + (g ^ ((row >> 1) & 3)) * 8;
  }
#pragma unroll
  for (int it = 0; it < 3; it++) {
    int idx = it * 256 + tid, row = idx >> 2, g = idx & 3;
    srcB[it] = wh + (size_t)row * 384 + (g ^ ((row >> 1) & 3)) * 8;
  }

#define STAGE(j)                                              \
  do {                                                        \
    u16* Ad = L + ((j) & 1) * 8192 + wv * 512;                \
    u16* Bd = L + 16384 + ((j) & 1) * 6144 + wv * 512;        \
    GLD16(srcA[0] + (j) * 32, Ad + 0 * 2048);                 \
    GLD16(srcA[1] + (j) * 32, Ad + 1 * 2048);                 \
    GLD16(srcA[2] + (j) * 32, Ad + 2 * 2048);                 \
    GLD16(srcA[3] + (j) * 32, Ad + 3 * 2048);                 \
    GLD16(srcB[0] + (j) * 32, Bd + 0 * 2048);                 \
    GLD16(srcB[1] + (j) * 32, Bd + 1 * 2048);                 \
    GLD16(srcB[2] + (j) * 32, Bd + 2 * 2048);                 \
  } while (0)

  int ra[4], rb[9];
#pragma unroll
  for (int i = 0; i < 4; i++) {
    int row = wv * 64 + i * 16 + lr;
    ra[i] = row * 32 + (lg ^ ((row >> 1) & 3)) * 8;
  }
#pragma unroll
  for (int i = 0; i < 9; i++) {
    int row = i * 16 + lr;
    rb[i] = row * 32 + (lg ^ ((row >> 1) & 3)) * 8;
  }

  f32x4 acc[4][9];
#pragma unroll
  for (int i = 0; i < 4; i++)
#pragma unroll
    for (int j = 0; j < 9; j++) acc[i][j] = (f32x4){0.f, 0.f, 0.f, 0.f};

  STAGE(0);
  VMCNT0();
  BARRIER();

#pragma unroll
  for (int ks = 0; ks < 12; ks++) {
    if (ks < 11) STAGE(ks + 1);
    const u16* Ab = L + (ks & 1) * 8192;
    const u16* Bb = L + 16384 + (ks & 1) * 6144;
    short8 af[4], bf[9];
#pragma unroll
    for (int mi = 0; mi < 4; mi++) af[mi] = *(const short8*)(Ab + ra[mi]);
#pragma unroll
    for (int ni = 0; ni < 9; ni++) bf[ni] = *(const short8*)(Bb + rb[ni]);
#pragma unroll
    for (int mi = 0; mi < 4; mi++)
#pragma unroll
      for (int ni = 0; ni < 9; ni++)
        acc[mi][ni] = MFMA(af[mi], bf[ni], acc[mi][ni]);
    if (ks < 11) {
      VMCNT0();
      BARRIER();
    }
  }
#undef STAGE
  __syncthreads();   // all staging reads done before q/k/vT overwrite LDS

  // ---------------- acc -> LDS q/k/vT ----------------
  if (tid < 16) L[KOFF + 14336 + tid] = 0;   // k band-overread pad (finite x 0)
  const float* bhp = bH + h * 192;
#pragma unroll
  for (int ni = 0; ni < 9; ni++) {
    int c = ni * 16 + lr;            // 0..143
    float bn = bhp[c];
#pragma unroll
    for (int mi = 0; mi < 4; mi++) {
      int t0 = wv * 64 + mi * 16 + lg * 4;
      f32x4 a = acc[mi][ni];
      if (ni < 3) {                  // q: [t][48] dense
#pragma unroll
        for (int r = 0; r < 4; r++)
          L[QOFF + (t0 + r) * 48 + c] = f2bf(a[r] + bn);
      } else if (ni < 6) {           // k: [t][56] (2-way-free banks)
#pragma unroll
        for (int r = 0; r < 4; r++)
          L[KOFF + (t0 + r) * 56 + (c - 48)] = f2bf(a[r] + bn);
      } else {                       // vT: [d][264]
        ushort4 o;
        o.x = f2bf(a[0] + bn); o.y = f2bf(a[1] + bn);
        o.z = f2bf(a[2] + bn); o.w = f2bf(a[3] + bn);
        *(ushort4*)&L[VOFF + (c - 96) * 264 + t0] = o;
      }
    }
  }
  __syncthreads();

  // ---------------- attention (round-10 code, LDS sources) ----------------
  const u16* mk = memK + h * 64 * 48;
  const u16* mv = memvT + h * 48 * 64;
  const f32x4 z4 = (f32x4){0.f, 0.f, 0.f, 0.f};

#pragma unroll 1
  for (int qi = 0; qi < 4; qi++) {
    int q0 = wv * 64 + qi * 16;
    int kthi = q0 >> 4;

    const u16* qrow = (const u16*)L + QOFF + (q0 + lr) * 48;
    short8 bq0 = *(const short8*)(qrow + lg * 8);
    short8 bq1 = (short8){0, 0, 0, 0, 0, 0, 0, 0};
    if (l < 32) bq1 = *(const short8*)(qrow + 32 + lg * 8);  // feats 32..47

    f32x4 s[9];
#pragma unroll
    for (int mt = 0; mt < 4; mt++) {  // mem tiles: always fully visible
      const u16* krow = mk + (mt * 16 + lr) * 48;
      short8 a0 = *(const short8*)(krow + lg * 8);
      short8 a1 = *(const short8*)(krow + 32 + lg * 8);
      f32x4 sv = MFMA(a0, bq0, z4);
      sv = MFMA(a1, bq1, sv);
      s[mt] = sv;
    }
    int i_q = q0 + lr;
#pragma unroll
    for (int u = 0; u < 5; u++) {  // band tiles kthi-4 .. kthi
      int kt = kthi - 4 + u;
      int kr = kt * 16 + lr;
      if (kr < 0) kr = 0;   // fully-masked tile: value irrelevant, in-bounds
      const u16* krow = (const u16*)L + KOFF + kr * 56;
      short8 a0 = *(const short8*)(krow + lg * 8);
      short8 a1 = *(const short8*)(krow + 32 + lg * 8);  // pad/next-row, x 0
      f32x4 sv = MFMA(a0, bq0, z4);
      sv = MFMA(a1, bq1, sv);
#pragma unroll
      for (int r = 0; r < 4; r++) {
        int jk = kt * 16 + lg * 4 + r;
        bool vis = (jk >= 0) && (jk <= i_q) && (i_q - jk <= 64);
        sv[r] = vis ? sv[r] : -1e30f;
      }
      s[4 + u] = sv;
    }

    // softmax over 36 scores/lane + cross-group (same q column) reduce
    float mx = -1e30f;
#pragma unroll
    for (int t = 0; t < 9; t++)
      mx = fmaxf(mx, fmaxf(fmaxf(s[t][0], s[t][1]), fmaxf(s[t][2], s[t][3])));
    mx = fmaxf(mx, __shfl_xor(mx, 16));
    mx = fmaxf(mx, __shfl_xor(mx, 32));
    float sum = 0.f;
#pragma unroll
    for (int t = 0; t < 9; t++) {
#pragma unroll
      for (int r = 0; r < 4; r++) {
        float p = exp2f(s[t][r] - mx);  // scores already in log2 domain
        s[t][r] = p;
        sum += p;
      }
    }
    sum += __shfl_xor(sum, 16);
    sum += __shfl_xor(sum, 32);
    float rinv = 1.f / sum;

    unsigned pk[9][2];
#pragma unroll
    for (int t = 0; t < 9; t++) {
      pk[t][0] = pack_bf16(s[t][0], s[t][1]);
      pk[t][1] = pack_bf16(s[t][2], s[t][3]);
    }

    f32x4 y0 = z4, y1 = z4, y2 = z4;
    auto pv = [&](const u16* vbase, int stride, int lane_ko, unsigned A0,
                  unsigned A1, unsigned B0, unsigned B1, bool hasB) {
      int srcL0 = lr + (lg & 1) * 32;
      int srcL1 = srcL0 + 16;
      bool hi = lg >= 2;
      unsigned a0 = __shfl(A0, srcL0, 64), a1 = __shfl(A1, srcL0, 64);
      unsigned a2 = __shfl(A0, srcL1, 64), a3 = __shfl(A1, srcL1, 64);
      unsigned w0, w1, w2, w3;
      if (hasB) {
        unsigned c0 = __shfl(B0, srcL0, 64), c1 = __shfl(B1, srcL0, 64);
        unsigned c2 = __shfl(B0, srcL1, 64), c3 = __shfl(B1, srcL1, 64);
        w0 = hi ? c0 : a0; w1 = hi ? c1 : a1; w2 = hi ? c2 : a2; w3 = hi ? c3 : a3;
      } else {
        w0 = hi ? 0u : a0; w1 = hi ? 0u : a1; w2 = hi ? 0u : a2; w3 = hi ? 0u : a3;
      }
      union { unsigned u[4]; short8 v; } bu;
      bu.u[0] = w0; bu.u[1] = w1; bu.u[2] = w2; bu.u[3] = w3;
      const u16* va0 = vbase + (0 * 16 + lr) * stride + lane_ko;
      const u16* va1 = vbase + (1 * 16 + lr) * stride + lane_ko;
      const u16* va2 = vbase + (2 * 16 + lr) * stride + lane_ko;
      y0 = MFMA(*(const short8*)va0, bu.v, y0);
      y1 = MFMA(*(const short8*)va1, bu.v, y1);
      y2 = MFMA(*(const short8*)va2, bu.v, y2);
    };
    pv(mv, 64, lg * 8, pk[0][0], pk[0][1], pk[1][0], pk[1][1], true);
    pv(mv + 32, 64, lg * 8, pk[2][0], pk[2][1], pk[3][0], pk[3][1], true);
    const u16* vbase = (const u16*)L + VOFF;
    const u16* vbb = vbase + (kthi - 4) * 16;  // kthi<4: negative offset lands
                                               // in k region (finite, x 0)
    pv(vbb, 264, lg * 8, pk[4][0], pk[4][1], pk[5][0], pk[5][1], true);
    pv(vbb + 32, 264, lg * 8, pk[6][0], pk[6][1], pk[7][0], pk[7][1], true);
    {
      int ko = kthi * 16 + lg * 8;
      if (ko > 248) ko = 0;   // clamp: value multiplies a zero B operand
      pv(vbase, 264, ko, pk[8][0], pk[8][1], 0u, 0u, false);
    }

    int t = q0 + lr;
    u16* yout = ybuf + ((size_t)(b * 256 + t)) * 384 + h * 48 + lg * 4;
    ushort4 o;
    o.x = f2bf(y0[0] * rinv); o.y = f2bf(y0[1] * rinv);
    o.z = f2bf(y0[2] * rinv); o.w = f2bf(y0[3] * rinv);
    *(ushort4*)(yout + 0) = o;
    o.x = f2bf(y1[0] * rinv); o.y = f2bf(y1[1] * rinv);
    o.z = f2bf(y1[2] * rinv); o.w = f2bf(y1[3] * rinv);
    *(ushort4*)(yout + 16) = o;
    o.x = f2bf(y2[0] * rinv); o.y = f2bf(y2[1] * rinv);
    o.z = f2bf(y2[2] * rinv); o.w = f2bf(y2[3] * rinv);
    *(ushort4*)(yout + 32) = o;
  }
}

// ------------------------------------------------------------------
// Output projection (round-10 exact, replay-proven).
// ------------------------------------------------------------------
__global__ __launch_bounds__(256, 3) void proj_gemm_kernel(
    const u16* __restrict__ y, const u16* __restrict__ wT,
    const float* __restrict__ bias, float* __restrict__ out) {
  __shared__ u16 Al[3][4096];
  __shared__ u16 Bl[3][4096];
  int tid = threadIdx.x, bx = blockIdx.x;
  int lid = (bx & 7) * 192 + (bx >> 3);  // 1536 = 8 * 192
  int mtile = lid / 3, ntile = lid - mtile * 3;
  int m0 = mtile * 128, n0 = ntile * 128;
  int l = tid & 63, wv = tid >> 6;
  int wr = wv >> 1, wc = wv & 1;
  int lr = l & 15, lg = l >> 4;

  int q = l >> 2, g = l & 3;
  int rA0 = wv * 32 + q, rA1 = rA0 + 16;
  const u16* sA0 = y + (size_t)(m0 + rA0) * 384 + (g ^ ((rA0 >> 1) & 3)) * 8;
  const u16* sA1 = y + (size_t)(m0 + rA1) * 384 + (g ^ ((rA1 >> 1) & 3)) * 8;
  const u16* sB0 = wT + (size_t)(n0 + rA0) * 384 + (g ^ ((rA0 >> 1) & 3)) * 8;
  const u16* sB1 = wT + (size_t)(n0 + rA1) * 384 + (g ^ ((rA1 >> 1) & 3)) * 8;

#define STAGE(j)                                          \
  do {                                                    \
    int b_ = (j) % 3;                                     \
    GLD16(sA0 + (j) * 32, &Al[b_][wv * 1024]);            \
    GLD16(sA1 + (j) * 32, &Al[b_][wv * 1024 + 512]);      \
    GLD16(sB0 + (j) * 32, &Bl[b_][wv * 1024]);            \
    GLD16(sB1 + (j) * 32, &Bl[b_][wv * 1024 + 512]);      \
  } while (0)

  int ra[4], rb[4];
#pragma unroll
  for (int i = 0; i < 4; i++) {
    int rA = wr * 64 + i * 16 + lr;
    ra[i] = rA * 32 + (lg ^ ((rA >> 1) & 3)) * 8;
    int rB = wc * 64 + i * 16 + lr;
    rb[i] = rB * 32 + (lg ^ ((rB >> 1) & 3)) * 8;
  }

  f32x4 acc[4][4];
#pragma unroll
  for (int i = 0; i < 4; i++)
#pragma unroll
    for (int j = 0; j < 4; j++) acc[i][j] = (f32x4){0.f, 0.f, 0.f, 0.f};

  STAGE(0);
  STAGE(1);
  VMCNT4();
  BARRIER();

#pragma unroll
  for (int k = 0; k < 12; k++) {
    if (k < 10) STAGE(k + 2);
    short8 af[4], bfr[4];
#pragma unroll
    for (int mi = 0; mi < 4; mi++) af[mi] = *(const short8*)&Al[k % 3][ra[mi]];
#pragma unroll
    for (int ni = 0; ni < 4; ni++) bfr[ni] = *(const short8*)&Bl[k % 3][rb[ni]];
#pragma unroll
    for (int mi = 0; mi < 4; mi++)
#pragma unroll
      for (int ni = 0; ni < 4; ni++)
        acc[mi][ni] = MFMA(af[mi], bfr[ni], acc[mi][ni]);
    if (k < 11) {
      if (k < 10) VMCNT4(); else VMCNT0();
      BARRIER();
    }
  }
#undef STAGE

#pragma unroll
  for (int ni = 0; ni < 4; ni++) {
    int n = n0 + wc * 64 + ni * 16 + lr;
    float bn = bias[n];
#pragma unroll
    for (int mi = 0; mi < 4; mi++) {
      int mrow = m0 + wr * 64 + mi * 16 + lg * 4;
      f32x4 a = acc[mi][ni];
#pragma unroll
      for (int r = 0; r < 4; r++)
        out[(size_t)(mrow + r) * 384 + n] = a[r] + bn;
    }
  }
}

// ------------------------------------------------------------------
extern "C" void kernel_launch(void* const* d_in, const int* in_sizes, int n_in,
                              void* d_out, int out_size, void* d_ws, size_t ws_size,
                              hipStream_t stream) {
  (void)in_sizes; (void)n_in; (void)out_size; (void)ws_size;
  const float* x = (const float*)d_in[0];
  const float* mem = (const float*)d_in[1];
  const float* qkv_w = (const float*)d_in[2];
  const float* qkv_b = (const float*)d_in[3];
  const float* proj_w = (const float*)d_in[4];
  const float* proj_b = (const float*)d_in[5];
  float* out = (float*)d_out;

  char* ws = (char*)d_ws;
  size_t off = 0;
  auto alloc = [&](size_t bytes) -> void* {
    void* p = (void*)(ws + off);
    off += (bytes + 255) & ~(size_t)255;
    return p;
  };
  u16* proj_wT = (u16*)alloc((size_t)384 * 384 * 2);
  u16* memK = (u16*)alloc((size_t)8 * 64 * 48 * 2);
  u16* memvT = (u16*)alloc((size_t)8 * 48 * 64 * 2);
  u16* wH = (u16*)alloc((size_t)8 * 192 * 384 * 2);
  float* bH = (float*)alloc((size_t)8 * 192 * 4);
  u16* xbf = (u16*)alloc((size_t)65536 * 384 * 2);   // NOT aliased with ybuf
  u16* ybuf = (u16*)alloc((size_t)65536 * 384 * 2);

  hipLaunchKernelGGL(prep_wT_kernel, dim3(36), dim3(256), 0, stream,
                     proj_w, proj_wT, 384, 384);
  hipLaunchKernelGGL(prep_mem_kernel, dim3(96), dim3(256), 0, stream,
                     mem, memK, memvT);
  hipLaunchKernelGGL(prep_wh_kernel, dim3(2304), dim3(256), 0, stream,
                     qkv_w, qkv_b, wH, bH);
  hipLaunchKernelGGL(prep_x_kernel, dim3(4096), dim3(256), 0, stream, x, xbf);
  hipLaunchKernelGGL(fused_qkv_attn_kernel, dim3(2048), dim3(256), 0, stream,
                     xbf, wH, bH, memK, memvT, ybuf);
  hipLaunchKernelGGL(proj_gemm_kernel, dim3(1536), dim3(256), 0, stream,
                     ybuf, proj_wT, proj_b, out);
}